// Round 5
// baseline (201.755 us; speedup 1.0000x reference)
//
#include <hip/hip_runtime.h>
#include <math.h>

#define IMG_H 96
#define IMG_W 96
#define HW (IMG_H * IMG_W)
#define XS 68   // LDS dword stride per x-column: 64 chans + 4 pad
                // conv b128 reads: bank-quad = (17*x + 4*o) mod 8 -> uniform (floor)

// sum over the 4 o-lanes of a quad (o = tid&3) via DPP quad_perm butterflies
__device__ __forceinline__ float quad_sum(float v) {
    v += __int_as_float(__builtin_amdgcn_update_dpp(
            0, __float_as_int(v), 0xB1, 0xF, 0xF, true));   // quad_perm [1,0,3,2]
    v += __int_as_float(__builtin_amdgcn_update_dpp(
            0, __float_as_int(v), 0x4E, 0xF, 0xF, true));   // quad_perm [2,3,0,1]
    return v;
}

// ---- build u_hat[32] for one (t, o) from conv raw outputs (bias pre-added) --
__device__ __forceinline__ void emit_uh(const float* rp, const float* ra,
                                        int o, int t, int w, int h,
                                        const float* __restrict__ Wp,
                                        const float* __restrict__ Wa,
                                        float* uh)
{
    float mn[16], ma[16];
    const float4* wp4 = (const float4*)(Wp + o * 128 + t * 16);
    const float4* wa4 = (const float4*)(Wa + o * 128 + t * 16);
    #pragma unroll
    for (int k = 0; k < 4; ++k) {
        float4 a = wp4[k];
        mn[4*k+0] = a.x; mn[4*k+1] = a.y; mn[4*k+2] = a.z; mn[4*k+3] = a.w;
        float4 b = wa4[k];
        ma[4*k+0] = b.x; ma[4*k+1] = b.y; ma[4*k+2] = b.z; ma[4*k+3] = b.w;
    }
    #pragma unroll
    for (int c = 0; c < 4; ++c) {   // column-normalize W_pos (axis=-2)
        float s = mn[c]*mn[c] + mn[4+c]*mn[4+c] + mn[8+c]*mn[8+c] + mn[12+c]*mn[12+c];
        float inv = 1.0f / sqrtf(fmaxf(s, 1e-12f));
        mn[c] *= inv; mn[4+c] *= inv; mn[8+c] *= inv; mn[12+c] *= inv;
    }
    mn[12] += (float)w * (1.0f / 96.0f);   // coord add [row3,col0] += x/W
    mn[13] += (float)h * (1.0f / 96.0f);   // [row3,col1] += y/H
    #pragma unroll
    for (int p0 = 0; p0 < 4; ++p0) {
        #pragma unroll
        for (int c = 0; c < 4; ++c) {
            uh[p0*4+c]    = rp[p0*4+0]*mn[c]   + rp[p0*4+1]*mn[4+c]
                          + rp[p0*4+2]*mn[8+c] + rp[p0*4+3]*mn[12+c];
            uh[16+p0*4+c] = ra[p0*4+0]*ma[c]   + ra[p0*4+1]*ma[4+c]
                          + ra[p0*4+2]*ma[8+c] + ra[p0*4+3]*ma[12+c];
        }
    }
}

// ---- 3-iter routing for one capsule; o summed across quad lanes -----------
__device__ __forceinline__ void route_store(const float* uh, int o, int nt,
                                            int pix, float* __restrict__ out)
{
    float bl = 0.0f;
    #pragma unroll
    for (int it = 0; it < 2; ++it) {       // two update iterations (single pass)
        float r = 1.0f / (1.0f + __expf(-bl));
        float mx = 0.0f, n2 = 0.0f, dp = 0.0f, da = 0.0f;
        #pragma unroll
        for (int z = 0; z < 16; ++z) {
            float p = quad_sum(uh[z] * r);
            mx = fmaxf(mx, fabsf(p));
            dp = fmaf(uh[z], p, dp);
        }
        #pragma unroll
        for (int z = 16; z < 32; ++z) {
            float p = quad_sum(uh[z] * r);
            n2 = fmaf(p, p, n2);
            da = fmaf(uh[z], p, da);
        }
        float invm = 1.0f / mx;                               // psquash
        float sc   = n2 / ((1.0f + n2) * sqrtf(n2 + 1e-9f));  // matwo squash
        bl += (invm * dp) * (sc * da);
    }
    // final iteration: need p values for the store
    float r = 1.0f / (1.0f + __expf(-bl));
    float p[32];
    float mx = 0.0f, n2 = 0.0f;
    #pragma unroll
    for (int z = 0; z < 16; ++z) {
        p[z] = quad_sum(uh[z] * r);
        mx = fmaxf(mx, fabsf(p[z]));
    }
    #pragma unroll
    for (int z = 16; z < 32; ++z) {
        p[z] = quad_sum(uh[z] * r);
        n2 = fmaf(p[z], p[z], n2);
    }
    float invm = 1.0f / mx;
    float sc   = n2 / ((1.0f + n2) * sqrtf(n2 + 1e-9f));
    float scale = (o < 2) ? invm : sc;
    float* op = out + ((size_t)nt * 32 + o * 8) * HW + pix;
    #pragma unroll
    for (int j = 0; j < 8; ++j) {          // select p[o*8+j] w/o dynamic indexing
        float lo = (o & 1) ? p[8+j]  : p[j];
        float hi = (o & 1) ? p[24+j] : p[16+j];
        float v  = (o & 2) ? hi : lo;
        op[(size_t)j * HW] = v * scale;
    }
}

// Block 256 = 32 px * 4 o * 2 tsub. Grid (3 wtiles, 96 h, 8 = n*2 + parity).
// One parity (z-half, 4 capsule types) per block: stage tile, conv 2 capsule
// types/thread (4 FMA per LDS value), emit u_hat in regs, route + store.
__global__ __launch_bounds__(256, 2)
void caps_one_kernel(const float* __restrict__ x,    // (4,4,32,96,96)
                     const float* __restrict__ Wc,   // (4,5,5,1,8)
                     const float* __restrict__ Wp,   // (4,16,8)
                     const float* __restrict__ Wa,   // (4,16,8)
                     const float* __restrict__ Ba,   // (4,8)
                     float* __restrict__ out)        // (4,8,32,96,96)
{
    __shared__ float tile[5 * 36 * XS];   // [dy][x][chan 64 (+4 pad)]  48.96 KB
    __shared__ float wsh[800];            // conv weights [o][k25][f8]

    const int tid    = threadIdx.x;
    const int o      = tid & 3;
    const int px     = (tid >> 2) & 31;
    const int tsub   = tid >> 7;
    const int wb     = blockIdx.x * 32;
    const int h      = blockIdx.y;
    const int n      = blockIdx.z >> 1;
    const int parity = blockIdx.z & 1;
    const int w      = wb + px;
    const int pix    = h * IMG_W + w;

    for (int i = tid; i < 800; i += 256) wsh[i] = Wc[i];

    // ---- staging: interior 32 cols (coalesced 128B rows) ----
    {
        const int col = tid & 31;
        const int r0  = tid >> 5;
        #pragma unroll 8
        for (int k = 0; k < 40; ++k) {
            int r  = r0 + (k << 3);          // r = dy*64 + c, 0..319
            int dy = r >> 6;
            int c  = r & 63;
            int hh = h + dy - 2;
            int chan = n * 128 + ((c >> 4) << 5) + (parity << 4) + (c & 15);
            float v = 0.0f;
            if ((unsigned)hh < IMG_H)
                v = x[(size_t)chan * HW + hh * IMG_W + wb + col];
            tile[(dy * 36 + 2 + col) * XS + c] = v;
        }
        // halo: x in {0,1,34,35}
        const int m  = tid & 3;
        const int xx = (m < 2) ? m : (m + 32);
        const int ww = wb - 2 + xx;
        const int r1 = tid >> 2;
        #pragma unroll 5
        for (int k = 0; k < 5; ++k) {
            int r  = r1 + (k << 6);
            int dy = r >> 6;
            int c  = r & 63;
            int hh = h + dy - 2;
            int chan = n * 128 + ((c >> 4) << 5) + (parity << 4) + (c & 15);
            float v = 0.0f;
            if ((unsigned)hh < IMG_H && (unsigned)ww < IMG_W)
                v = x[(size_t)chan * HW + hh * IMG_W + ww];
            tile[(dy * 36 + xx) * XS + c] = v;
        }
    }
    __syncthreads();

    // ---- conv 5x5: 2 capsule types per thread, 16 q via 4x ds_read_b128 ----
    float rpa[16], rpb[16], raa[16], rab[16];
    #pragma unroll
    for (int q = 0; q < 16; ++q) { rpa[q]=0.f; rpb[q]=0.f; raa[q]=0.f; rab[q]=0.f; }

    const float* wbase = &wsh[o * 200 + (tsub << 1)];
    #pragma unroll 1
    for (int dy = 0; dy < 5; ++dy) {
        #pragma unroll
        for (int dx = 0; dx < 5; ++dx) {
            const float4* t4 =
                (const float4*)&tile[(dy * 36 + px + dx) * XS + (o << 4)];
            float4 q0 = t4[0], q1 = t4[1], q2 = t4[2], q3 = t4[3];
            const float* wr = wbase + dy * 40 + dx * 8;
            float wpa = wr[0], wpb = wr[1], waa = wr[4], wab = wr[5];
            float qq[16] = {q0.x,q0.y,q0.z,q0.w, q1.x,q1.y,q1.z,q1.w,
                            q2.x,q2.y,q2.z,q2.w, q3.x,q3.y,q3.z,q3.w};
            #pragma unroll
            for (int q = 0; q < 16; ++q) {
                rpa[q] = fmaf(qq[q], wpa, rpa[q]);
                rpb[q] = fmaf(qq[q], wpb, rpb[q]);
                raa[q] = fmaf(qq[q], waa, raa[q]);
                rab[q] = fmaf(qq[q], wab, rab[q]);
            }
        }
    }

    const int t_a = parity + 4 * tsub;
    const int t_b = t_a + 2;
    const float ba_a = Ba[o * 8 + t_a];
    const float ba_b = Ba[o * 8 + t_b];
    #pragma unroll
    for (int q = 0; q < 16; ++q) { raa[q] += ba_a; rab[q] += ba_b; }

    // emit both capsules first so conv accumulators are dead before routing
    float uhA[32], uhB[32];
    emit_uh(rpa, raa, o, t_a, w, h, Wp, Wa, uhA);
    emit_uh(rpb, rab, o, t_b, w, h, Wp, Wa, uhB);

    route_store(uhA, o, n * 8 + t_a, pix, out);
    route_store(uhB, o, n * 8 + t_b, pix, out);
}

extern "C" void kernel_launch(void* const* d_in, const int* in_sizes, int n_in,
                              void* d_out, int out_size, void* d_ws, size_t ws_size,
                              hipStream_t stream) {
    const float* x  = (const float*)d_in[0];
    const float* Wc = (const float*)d_in[1];
    const float* Wp = (const float*)d_in[2];
    const float* Wa = (const float*)d_in[3];
    const float* Ba = (const float*)d_in[4];
    float* outp = (float*)d_out;

    caps_one_kernel<<<dim3(3, 96, 8), 256, 0, stream>>>(x, Wc, Wp, Wa, Ba, outp);
}

// Round 6
// 162.392 us; speedup vs baseline: 1.2424x; 1.2424x over previous
//
#include <hip/hip_runtime.h>
#include <hip/hip_fp16.h>
#include <math.h>

#define IMG_H 96
#define IMG_W 96
#define HW (IMG_H * IMG_W)
#define TS2 36   // half2 (dword) stride per x-column: 32 chan-pairs + 4 pad
// conv b128 reads: start bank = (4x + 8o) mod 32 -> uniform 8 lanes/bank = floor

// sum over the 4 o-lanes of a quad (o = tid&3) via DPP quad_perm butterflies
__device__ __forceinline__ float quad_sum(float v) {
    v += __int_as_float(__builtin_amdgcn_update_dpp(
            0, __float_as_int(v), 0xB1, 0xF, 0xF, true));   // quad_perm [1,0,3,2]
    v += __int_as_float(__builtin_amdgcn_update_dpp(
            0, __float_as_int(v), 0x4E, 0xF, 0xF, true));   // quad_perm [2,3,0,1]
    return v;
}

// ---- build u_hat[32] for one (t, o) from conv raw outputs (bias pre-added) --
__device__ __forceinline__ void emit_uh(const float* rp, const float* ra,
                                        int o, int t, int w, int h,
                                        const float* __restrict__ Wp,
                                        const float* __restrict__ Wa,
                                        float* uh)
{
    float mn[16], ma[16];
    const float4* wp4 = (const float4*)(Wp + o * 128 + t * 16);
    const float4* wa4 = (const float4*)(Wa + o * 128 + t * 16);
    #pragma unroll
    for (int k = 0; k < 4; ++k) {
        float4 a = wp4[k];
        mn[4*k+0] = a.x; mn[4*k+1] = a.y; mn[4*k+2] = a.z; mn[4*k+3] = a.w;
        float4 b = wa4[k];
        ma[4*k+0] = b.x; ma[4*k+1] = b.y; ma[4*k+2] = b.z; ma[4*k+3] = b.w;
    }
    #pragma unroll
    for (int c = 0; c < 4; ++c) {   // column-normalize W_pos (axis=-2)
        float s = mn[c]*mn[c] + mn[4+c]*mn[4+c] + mn[8+c]*mn[8+c] + mn[12+c]*mn[12+c];
        float inv = 1.0f / sqrtf(fmaxf(s, 1e-12f));
        mn[c] *= inv; mn[4+c] *= inv; mn[8+c] *= inv; mn[12+c] *= inv;
    }
    mn[12] += (float)w * (1.0f / 96.0f);   // coord add [row3,col0] += x/W
    mn[13] += (float)h * (1.0f / 96.0f);   // [row3,col1] += y/H
    #pragma unroll
    for (int p0 = 0; p0 < 4; ++p0) {
        #pragma unroll
        for (int c = 0; c < 4; ++c) {
            uh[p0*4+c]    = rp[p0*4+0]*mn[c]   + rp[p0*4+1]*mn[4+c]
                          + rp[p0*4+2]*mn[8+c] + rp[p0*4+3]*mn[12+c];
            uh[16+p0*4+c] = ra[p0*4+0]*ma[c]   + ra[p0*4+1]*ma[4+c]
                          + ra[p0*4+2]*ma[8+c] + ra[p0*4+3]*ma[12+c];
        }
    }
}

// ---- 3-iter routing for one capsule; o summed across quad lanes -----------
__device__ __forceinline__ void route_store(const float* uh, int o, int nt,
                                            int pix, float* __restrict__ out)
{
    float bl = 0.0f;
    #pragma unroll
    for (int it = 0; it < 2; ++it) {       // two update iterations (single pass)
        float r = 1.0f / (1.0f + __expf(-bl));
        float mx = 0.0f, n2 = 0.0f, dp = 0.0f, da = 0.0f;
        #pragma unroll
        for (int z = 0; z < 16; ++z) {
            float p = quad_sum(uh[z] * r);
            mx = fmaxf(mx, fabsf(p));
            dp = fmaf(uh[z], p, dp);
        }
        #pragma unroll
        for (int z = 16; z < 32; ++z) {
            float p = quad_sum(uh[z] * r);
            n2 = fmaf(p, p, n2);
            da = fmaf(uh[z], p, da);
        }
        float invm = 1.0f / mx;                               // psquash
        float sc   = n2 / ((1.0f + n2) * sqrtf(n2 + 1e-9f));  // matwo squash
        bl += (invm * dp) * (sc * da);
    }
    // final iteration: need p values for the store
    float r = 1.0f / (1.0f + __expf(-bl));
    float p[32];
    float mx = 0.0f, n2 = 0.0f;
    #pragma unroll
    for (int z = 0; z < 16; ++z) {
        p[z] = quad_sum(uh[z] * r);
        mx = fmaxf(mx, fabsf(p[z]));
    }
    #pragma unroll
    for (int z = 16; z < 32; ++z) {
        p[z] = quad_sum(uh[z] * r);
        n2 = fmaf(p[z], p[z], n2);
    }
    float invm = 1.0f / mx;
    float sc   = n2 / ((1.0f + n2) * sqrtf(n2 + 1e-9f));
    float scale = (o < 2) ? invm : sc;
    float* op = out + ((size_t)nt * 32 + o * 8) * HW + pix;
    #pragma unroll
    for (int j = 0; j < 8; ++j) {          // select p[o*8+j] w/o dynamic indexing
        float lo = (o & 1) ? p[8+j]  : p[j];
        float hi = (o & 1) ? p[24+j] : p[16+j];
        float v  = (o & 2) ? hi : lo;
        op[(size_t)j * HW] = v * scale;
    }
}

// Block 256 = 32 px * 4 o * 2 tsub. Grid (3 wtiles, 96 h, 8 = n*2 + parity).
// fp16-packed conv: tile in LDS as half2 (2 q-chans/dword), v_pk_fma_f16,
// fp32 everywhere downstream.
__global__ __launch_bounds__(256, 4)
void caps_one_kernel(const float* __restrict__ x,    // (4,4,32,96,96)
                     const float* __restrict__ Wc,   // (4,5,5,1,8)
                     const float* __restrict__ Wp,   // (4,16,8)
                     const float* __restrict__ Wa,   // (4,16,8)
                     const float* __restrict__ Ba,   // (4,8)
                     float* __restrict__ out)        // (4,8,32,96,96)
{
    __shared__ __half2 tile2[5 * 36 * TS2];   // [dy][x][cp 32 (+4 pad)] 25.9 KB
    __shared__ __half2 wsh2[800];             // conv weights dup'd: [o][k25][f8]

    const int tid    = threadIdx.x;
    const int o      = tid & 3;
    const int px     = (tid >> 2) & 31;
    const int tsub   = tid >> 7;
    const int wb     = blockIdx.x * 32;
    const int h      = blockIdx.y;
    const int n      = blockIdx.z >> 1;
    const int parity = blockIdx.z & 1;
    const int w      = wb + px;
    const int pix    = h * IMG_W + w;

    for (int i = tid; i < 800; i += 256) wsh2[i] = __float2half2_rn(Wc[i]);

    // ---- staging: interior 32 cols, pairs of adjacent q-channels ----
    {
        const int col = tid & 31;
        const int r0  = tid >> 5;
        #pragma unroll 4
        for (int k = 0; k < 20; ++k) {
            int r  = r0 + (k << 3);          // r = dy*32 + cp, 0..159
            int dy = r >> 5;
            int cp = r & 31;
            int hh = h + dy - 2;
            int c0 = cp << 1;
            int chan = n * 128 + ((c0 >> 4) << 5) + (parity << 4) + (c0 & 15);
            float v0 = 0.0f, v1 = 0.0f;
            if ((unsigned)hh < IMG_H) {
                const float* src = x + (size_t)chan * HW + hh * IMG_W + wb + col;
                v0 = src[0];
                v1 = src[HW];
            }
            tile2[(dy * 36 + 2 + col) * TS2 + cp] = __floats2half2_rn(v0, v1);
        }
        // halo: x in {0,1,34,35}
        const int m  = tid & 3;
        const int xx = (m < 2) ? m : (m + 32);
        const int ww = wb - 2 + xx;
        const int rh = tid >> 2;
        #pragma unroll
        for (int k = 0; k < 3; ++k) {
            int r = rh + (k << 6);
            if (r < 160) {
                int dy = r >> 5;
                int cp = r & 31;
                int hh = h + dy - 2;
                int c0 = cp << 1;
                int chan = n * 128 + ((c0 >> 4) << 5) + (parity << 4) + (c0 & 15);
                float v0 = 0.0f, v1 = 0.0f;
                if ((unsigned)hh < IMG_H && (unsigned)ww < IMG_W) {
                    const float* src = x + (size_t)chan * HW + hh * IMG_W + ww;
                    v0 = src[0];
                    v1 = src[HW];
                }
                tile2[(dy * 36 + xx) * TS2 + cp] = __floats2half2_rn(v0, v1);
            }
        }
    }
    __syncthreads();

    // ---- conv 5x5: 2 capsule types per thread, packed fp16 (2 q per FMA) ----
    __half2 rp2a[8], rp2b[8], ra2a[8], ra2b[8];
    const __half2 z2 = __float2half2_rn(0.0f);
    #pragma unroll
    for (int i = 0; i < 8; ++i) { rp2a[i]=z2; rp2b[i]=z2; ra2a[i]=z2; ra2b[i]=z2; }

    const int wbi = o * 200 + (tsub << 1);
    #pragma unroll 1
    for (int dy = 0; dy < 5; ++dy) {
        #pragma unroll
        for (int dx = 0; dx < 5; ++dx) {
            const __half2* t2 = &tile2[(dy * 36 + px + dx) * TS2 + (o << 3)];
            union { uint4 u; __half2 hh[4]; } A, B;
            A.u = *(const uint4*)t2;
            B.u = *(const uint4*)(t2 + 4);
            const __half2* wr = &wsh2[wbi + dy * 40 + dx * 8];
            __half2 wpa = wr[0], wpb = wr[1], waa = wr[4], wab = wr[5];
            #pragma unroll
            for (int i = 0; i < 4; ++i) {
                rp2a[i]   = __hfma2(A.hh[i], wpa, rp2a[i]);
                rp2b[i]   = __hfma2(A.hh[i], wpb, rp2b[i]);
                ra2a[i]   = __hfma2(A.hh[i], waa, ra2a[i]);
                ra2b[i]   = __hfma2(A.hh[i], wab, ra2b[i]);
                rp2a[4+i] = __hfma2(B.hh[i], wpa, rp2a[4+i]);
                rp2b[4+i] = __hfma2(B.hh[i], wpb, rp2b[4+i]);
                ra2a[4+i] = __hfma2(B.hh[i], waa, ra2a[4+i]);
                ra2b[4+i] = __hfma2(B.hh[i], wab, ra2b[4+i]);
            }
        }
    }

    const int t_a = parity + 4 * tsub;
    const int t_b = t_a + 2;

    {   // capsule t_a fully first (its accumulators die before t_b's emit)
        float rp[16], ra[16];
        const float ba_a = Ba[o * 8 + t_a];
        #pragma unroll
        for (int i = 0; i < 8; ++i) {
            rp[2*i]   = __low2float(rp2a[i]);
            rp[2*i+1] = __high2float(rp2a[i]);
            ra[2*i]   = __low2float(ra2a[i]) + ba_a;
            ra[2*i+1] = __high2float(ra2a[i]) + ba_a;
        }
        float uh[32];
        emit_uh(rp, ra, o, t_a, w, h, Wp, Wa, uh);
        route_store(uh, o, n * 8 + t_a, pix, out);
    }
    {
        float rp[16], ra[16];
        const float ba_b = Ba[o * 8 + t_b];
        #pragma unroll
        for (int i = 0; i < 8; ++i) {
            rp[2*i]   = __low2float(rp2b[i]);
            rp[2*i+1] = __high2float(rp2b[i]);
            ra[2*i]   = __low2float(ra2b[i]) + ba_b;
            ra[2*i+1] = __high2float(ra2b[i]) + ba_b;
        }
        float uh[32];
        emit_uh(rp, ra, o, t_b, w, h, Wp, Wa, uh);
        route_store(uh, o, n * 8 + t_b, pix, out);
    }
}

extern "C" void kernel_launch(void* const* d_in, const int* in_sizes, int n_in,
                              void* d_out, int out_size, void* d_ws, size_t ws_size,
                              hipStream_t stream) {
    const float* x  = (const float*)d_in[0];
    const float* Wc = (const float*)d_in[1];
    const float* Wp = (const float*)d_in[2];
    const float* Wa = (const float*)d_in[3];
    const float* Ba = (const float*)d_in[4];
    float* outp = (float*)d_out;

    caps_one_kernel<<<dim3(3, 96, 8), 256, 0, stream>>>(x, Wc, Wp, Wa, Ba, outp);
}

// Round 7
// 150.738 us; speedup vs baseline: 1.3384x; 1.0773x over previous
//
#include <hip/hip_runtime.h>
#include <hip/hip_fp16.h>
#include <math.h>

#define IMG_H 96
#define IMG_W 96
#define HW (IMG_H * IMG_W)
#define TS2 36   // half2 (dword) stride per x-column: 32 chan-pairs + 4 pad
// conv b128 reads + staging b128 writes: uniform 8 lanes per bank-quad = floor

// sum over the 4 o-lanes of a quad (o = tid&3) via DPP quad_perm butterflies
__device__ __forceinline__ float quad_sum(float v) {
    v += __int_as_float(__builtin_amdgcn_update_dpp(
            0, __float_as_int(v), 0xB1, 0xF, 0xF, true));   // quad_perm [1,0,3,2]
    v += __int_as_float(__builtin_amdgcn_update_dpp(
            0, __float_as_int(v), 0x4E, 0xF, 0xF, true));   // quad_perm [2,3,0,1]
    return v;
}

// ---- pos half: column-normalized W_pos + coord add, 4x4 matmul ------------
__device__ __forceinline__ void emit_pos(const float* rp, int o, int t,
                                         int w, int h,
                                         const float* __restrict__ Wp,
                                         float* uh)   // uh[0..16)
{
    float mn[16];
    const float4* wp4 = (const float4*)(Wp + o * 128 + t * 16);
    #pragma unroll
    for (int k = 0; k < 4; ++k) {
        float4 a = wp4[k];
        mn[4*k+0] = a.x; mn[4*k+1] = a.y; mn[4*k+2] = a.z; mn[4*k+3] = a.w;
    }
    #pragma unroll
    for (int c = 0; c < 4; ++c) {   // column-normalize (axis=-2)
        float s = mn[c]*mn[c] + mn[4+c]*mn[4+c] + mn[8+c]*mn[8+c] + mn[12+c]*mn[12+c];
        float inv = 1.0f / sqrtf(fmaxf(s, 1e-12f));
        mn[c] *= inv; mn[4+c] *= inv; mn[8+c] *= inv; mn[12+c] *= inv;
    }
    mn[12] += (float)w * (1.0f / 96.0f);   // coord add [row3,col0] += x/W
    mn[13] += (float)h * (1.0f / 96.0f);   // [row3,col1] += y/H
    #pragma unroll
    for (int p0 = 0; p0 < 4; ++p0)
        #pragma unroll
        for (int c = 0; c < 4; ++c)
            uh[p0*4+c] = rp[p0*4+0]*mn[c]   + rp[p0*4+1]*mn[4+c]
                       + rp[p0*4+2]*mn[8+c] + rp[p0*4+3]*mn[12+c];
}

// ---- app half: raw W_app 4x4 matmul (bias already added to ra) ------------
__device__ __forceinline__ void emit_app(const float* ra, int o, int t,
                                         const float* __restrict__ Wa,
                                         float* uh)   // uh[16..32)
{
    float ma[16];
    const float4* wa4 = (const float4*)(Wa + o * 128 + t * 16);
    #pragma unroll
    for (int k = 0; k < 4; ++k) {
        float4 b = wa4[k];
        ma[4*k+0] = b.x; ma[4*k+1] = b.y; ma[4*k+2] = b.z; ma[4*k+3] = b.w;
    }
    #pragma unroll
    for (int p0 = 0; p0 < 4; ++p0)
        #pragma unroll
        for (int c = 0; c < 4; ++c)
            uh[16+p0*4+c] = ra[p0*4+0]*ma[c]   + ra[p0*4+1]*ma[4+c]
                          + ra[p0*4+2]*ma[8+c] + ra[p0*4+3]*ma[12+c];
}

// ---- 3-iter routing for one capsule; o summed across quad lanes -----------
__device__ __forceinline__ void route_store(const float* uh, int o, int nt,
                                            int pix, float* __restrict__ out)
{
    float bl = 0.0f;
    #pragma unroll
    for (int it = 0; it < 2; ++it) {       // two update iterations (single pass)
        float r = 1.0f / (1.0f + __expf(-bl));
        float mx = 0.0f, n2 = 0.0f, dp = 0.0f, da = 0.0f;
        #pragma unroll
        for (int z = 0; z < 16; ++z) {
            float p = quad_sum(uh[z] * r);
            mx = fmaxf(mx, fabsf(p));
            dp = fmaf(uh[z], p, dp);
        }
        #pragma unroll
        for (int z = 16; z < 32; ++z) {
            float p = quad_sum(uh[z] * r);
            n2 = fmaf(p, p, n2);
            da = fmaf(uh[z], p, da);
        }
        float invm = 1.0f / mx;                               // psquash
        float sc   = n2 / ((1.0f + n2) * sqrtf(n2 + 1e-9f));  // matwo squash
        bl += (invm * dp) * (sc * da);
    }
    // final iteration: need p values for the store
    float r = 1.0f / (1.0f + __expf(-bl));
    float p[32];
    float mx = 0.0f, n2 = 0.0f;
    #pragma unroll
    for (int z = 0; z < 16; ++z) {
        p[z] = quad_sum(uh[z] * r);
        mx = fmaxf(mx, fabsf(p[z]));
    }
    #pragma unroll
    for (int z = 16; z < 32; ++z) {
        p[z] = quad_sum(uh[z] * r);
        n2 = fmaf(p[z], p[z], n2);
    }
    float invm = 1.0f / mx;
    float sc   = n2 / ((1.0f + n2) * sqrtf(n2 + 1e-9f));
    float scale = (o < 2) ? invm : sc;
    float* op = out + ((size_t)nt * 32 + o * 8) * HW + pix;
    #pragma unroll
    for (int j = 0; j < 8; ++j) {          // select p[o*8+j] w/o dynamic indexing
        float lo = (o & 1) ? p[8+j]  : p[j];
        float hi = (o & 1) ? p[24+j] : p[16+j];
        float v  = (o & 2) ? hi : lo;
        op[(size_t)j * HW] = v * scale;
    }
}

// Block 256 = 32 px * 4 o * 2 tsub. Grid (3 wtiles, 96 h, 8 = n*2 + parity).
__global__ void __launch_bounds__(256)
__attribute__((amdgpu_waves_per_eu(4, 4)))
caps_one_kernel(const float* __restrict__ x,    // (4,4,32,96,96)
                const float* __restrict__ Wc,   // (4,5,5,1,8)
                const float* __restrict__ Wp,   // (4,16,8)
                const float* __restrict__ Wa,   // (4,16,8)
                const float* __restrict__ Ba,   // (4,8)
                float* __restrict__ out)        // (4,8,32,96,96)
{
    __shared__ __half2 tile2[5 * 36 * TS2];   // [dy][x][cp 32 (+4 pad)] 25.9 KB
    __shared__ __half2 wsh2[800];             // conv weights dup'd: [o][k25][f8]

    const int tid    = threadIdx.x;
    const int o      = tid & 3;
    const int px     = (tid >> 2) & 31;
    const int tsub   = tid >> 7;
    const int wb     = blockIdx.x * 32;
    const int h      = blockIdx.y;
    const int n      = blockIdx.z >> 1;
    const int parity = blockIdx.z & 1;
    const int w      = wb + px;
    const int pix    = h * IMG_W + w;

    for (int i = tid; i < 800; i += 256) wsh2[i] = __float2half2_rn(Wc[i]);

    // ---- staging: interior 32 cols, 8 planes -> one ds_write_b128 ----
    {
        const int col = tid & 31;
        const int g8  = tid >> 5;            // 0..7
        #pragma unroll
        for (int k = 0; k < 5; ++k) {
            int rr  = g8 + (k << 3);         // 0..39 = dy*8 + cpg
            int dy  = rr >> 3;
            int cpg = rr & 7;
            int hh  = h + dy - 2;
            int c0  = cpg << 3;              // first of 8 consecutive chans
            int chan = n * 128 + ((c0 >> 4) << 5) + (parity << 4) + (c0 & 15);
            float v[8];
            #pragma unroll
            for (int j = 0; j < 8; ++j) v[j] = 0.0f;
            if ((unsigned)hh < IMG_H) {
                const float* src = x + (size_t)chan * HW + hh * IMG_W + wb + col;
                #pragma unroll
                for (int j = 0; j < 8; ++j) v[j] = src[(size_t)j * HW];
            }
            __half2 h4[4];
            #pragma unroll
            for (int j = 0; j < 4; ++j) h4[j] = __floats2half2_rn(v[2*j], v[2*j+1]);
            *(uint4*)&tile2[(dy * 36 + 2 + col) * TS2 + (cpg << 2)] = *(const uint4*)h4;
        }
        // halo: x in {0,1,34,35}
        const int m  = tid & 3;
        const int xx = (m < 2) ? m : (m + 32);
        const int ww = wb - 2 + xx;
        const int rh = tid >> 2;
        #pragma unroll
        for (int k = 0; k < 3; ++k) {
            int r = rh + (k << 6);
            if (r < 160) {
                int dy = r >> 5;
                int cp = r & 31;
                int hh = h + dy - 2;
                int c0 = cp << 1;
                int chan = n * 128 + ((c0 >> 4) << 5) + (parity << 4) + (c0 & 15);
                float v0 = 0.0f, v1 = 0.0f;
                if ((unsigned)hh < IMG_H && (unsigned)ww < IMG_W) {
                    const float* src = x + (size_t)chan * HW + hh * IMG_W + ww;
                    v0 = src[0];
                    v1 = src[HW];
                }
                tile2[(dy * 36 + xx) * TS2 + cp] = __floats2half2_rn(v0, v1);
            }
        }
    }
    __syncthreads();

    // ---- conv 5x5: 2 capsule types per thread, packed fp16 (2 q per FMA) ----
    __half2 rp2a[8], rp2b[8], ra2a[8], ra2b[8];
    const __half2 z2 = __float2half2_rn(0.0f);
    #pragma unroll
    for (int i = 0; i < 8; ++i) { rp2a[i]=z2; rp2b[i]=z2; ra2a[i]=z2; ra2b[i]=z2; }

    const int wbi = o * 200 + (tsub << 1);
    #pragma unroll 1
    for (int dy = 0; dy < 5; ++dy) {
        #pragma unroll
        for (int dx = 0; dx < 5; ++dx) {
            const __half2* t2 = &tile2[(dy * 36 + px + dx) * TS2 + (o << 3)];
            union { uint4 u; __half2 hh[4]; } A, B;
            A.u = *(const uint4*)t2;
            B.u = *(const uint4*)(t2 + 4);
            const __half2* wr = &wsh2[wbi + dy * 40 + dx * 8];
            __half2 wpa = wr[0], wpb = wr[1], waa = wr[4], wab = wr[5];
            #pragma unroll
            for (int i = 0; i < 4; ++i) {
                rp2a[i]   = __hfma2(A.hh[i], wpa, rp2a[i]);
                rp2b[i]   = __hfma2(A.hh[i], wpb, rp2b[i]);
                ra2a[i]   = __hfma2(A.hh[i], waa, ra2a[i]);
                ra2b[i]   = __hfma2(A.hh[i], wab, ra2b[i]);
                rp2a[4+i] = __hfma2(B.hh[i], wpa, rp2a[4+i]);
                rp2b[4+i] = __hfma2(B.hh[i], wpb, rp2b[4+i]);
                ra2a[4+i] = __hfma2(B.hh[i], waa, ra2a[4+i]);
                ra2b[4+i] = __hfma2(B.hh[i], wab, ra2b[4+i]);
            }
        }
    }

    const int t_a = parity + 4 * tsub;
    const int t_b = t_a + 2;

    {   // capsule t_a fully first (phase-split: pos regs die before app's)
        float uh[32];
        {
            float rp[16];
            #pragma unroll
            for (int i = 0; i < 8; ++i) {
                rp[2*i]   = __low2float(rp2a[i]);
                rp[2*i+1] = __high2float(rp2a[i]);
            }
            emit_pos(rp, o, t_a, w, h, Wp, uh);
        }
        {
            float ra[16];
            const float ba = Ba[o * 8 + t_a];
            #pragma unroll
            for (int i = 0; i < 8; ++i) {
                ra[2*i]   = __low2float(ra2a[i]) + ba;
                ra[2*i+1] = __high2float(ra2a[i]) + ba;
            }
            emit_app(ra, o, t_a, Wa, uh);
        }
        route_store(uh, o, n * 8 + t_a, pix, out);
    }
    {
        float uh[32];
        {
            float rp[16];
            #pragma unroll
            for (int i = 0; i < 8; ++i) {
                rp[2*i]   = __low2float(rp2b[i]);
                rp[2*i+1] = __high2float(rp2b[i]);
            }
            emit_pos(rp, o, t_b, w, h, Wp, uh);
        }
        {
            float ra[16];
            const float ba = Ba[o * 8 + t_b];
            #pragma unroll
            for (int i = 0; i < 8; ++i) {
                ra[2*i]   = __low2float(ra2b[i]) + ba;
                ra[2*i+1] = __high2float(ra2b[i]) + ba;
            }
            emit_app(ra, o, t_b, Wa, uh);
        }
        route_store(uh, o, n * 8 + t_b, pix, out);
    }
}

extern "C" void kernel_launch(void* const* d_in, const int* in_sizes, int n_in,
                              void* d_out, int out_size, void* d_ws, size_t ws_size,
                              hipStream_t stream) {
    const float* x  = (const float*)d_in[0];
    const float* Wc = (const float*)d_in[1];
    const float* Wp = (const float*)d_in[2];
    const float* Wa = (const float*)d_in[3];
    const float* Ba = (const float*)d_in[4];
    float* outp = (float*)d_out;

    caps_one_kernel<<<dim3(3, 96, 8), 256, 0, stream>>>(x, Wc, Wp, Wa, Ba, outp);
}

// Round 8
// 140.841 us; speedup vs baseline: 1.4325x; 1.0703x over previous
//
#include <hip/hip_runtime.h>
#include <hip/hip_fp16.h>
#include <math.h>

#define IMG_H 96
#define IMG_W 96
#define HW (IMG_H * IMG_W)
#define TW 16          // output w-tile per block
#define TC 20          // tile cols = TW + 4 halo
#define TS2 36         // half2 stride per x-column: 32 chan-pairs + 4 pad

// sum over the 4 o-lanes of a quad (o = tid&3) via DPP quad_perm butterflies
__device__ __forceinline__ float quad_sum(float v) {
    v += __int_as_float(__builtin_amdgcn_update_dpp(
            0, __float_as_int(v), 0xB1, 0xF, 0xF, true));   // quad_perm [1,0,3,2]
    v += __int_as_float(__builtin_amdgcn_update_dpp(
            0, __float_as_int(v), 0x4E, 0xF, 0xF, true));   // quad_perm [2,3,0,1]
    return v;
}

// 3-iter dynamic routing; o summed across quad lanes; final pass recomputes
// p per z and exec-mask-stores (no p[32] array -> low register peak).
__device__ __forceinline__ void route_store(const float* uh, int o, int nt,
                                            int pix, float* __restrict__ out)
{
    float bl = 0.0f;
    #pragma unroll
    for (int it = 0; it < 2; ++it) {
        float r = 1.0f / (1.0f + __expf(-bl));
        float mx = 0.0f, n2 = 0.0f, dp = 0.0f, da = 0.0f;
        #pragma unroll
        for (int z = 0; z < 16; ++z) {
            float p = quad_sum(uh[z] * r);
            mx = fmaxf(mx, fabsf(p));
            dp = fmaf(uh[z], p, dp);
        }
        #pragma unroll
        for (int z = 16; z < 32; ++z) {
            float p = quad_sum(uh[z] * r);
            n2 = fmaf(p, p, n2);
            da = fmaf(uh[z], p, da);
        }
        float invm = 1.0f / mx;                               // psquash
        float sc   = n2 / ((1.0f + n2) * sqrtf(n2 + 1e-9f));  // matwo squash
        bl += (invm * dp) * (sc * da);
    }
    float r = 1.0f / (1.0f + __expf(-bl));
    float mx = 0.0f, n2 = 0.0f;
    #pragma unroll
    for (int z = 0; z < 16; ++z) {
        float p = quad_sum(uh[z] * r);
        mx = fmaxf(mx, fabsf(p));
    }
    #pragma unroll
    for (int z = 16; z < 32; ++z) {
        float p = quad_sum(uh[z] * r);
        n2 = fmaf(p, p, n2);
    }
    float invm  = 1.0f / mx;
    float sc    = n2 / ((1.0f + n2) * sqrtf(n2 + 1e-9f));
    float scale = (o < 2) ? invm : sc;
    float* op = out + (size_t)nt * 32 * HW + pix;
    #pragma unroll
    for (int z = 0; z < 32; ++z) {
        float p = quad_sum(uh[z] * r);     // all lanes participate in the sum
        if ((z >> 3) == o)                  // only owning lanes store
            op[(size_t)z * HW] = p * scale;
    }
}

// Block 256 = 4 o (lane&3) x 16 px x 4 t (wave index). Grid (6, 96, n*2+parity).
__global__ void __launch_bounds__(256)
caps_one_kernel(const float* __restrict__ x,    // (4,4,32,96,96)
                const float* __restrict__ Wc,   // (4,5,5,1,8)
                const float* __restrict__ Wp,   // (4,16,8)
                const float* __restrict__ Wa,   // (4,16,8)
                const float* __restrict__ Ba,   // (4,8)
                float* __restrict__ out)        // (4,8,32,96,96)
{
    __shared__ __align__(16) __half2 tile2[5 * TC * TS2];  // 14.4 KB
    __shared__ __align__(16) __half2 wpk[400];  // (o*4+f)*25+k : (pos,app)
    __shared__ __align__(16) float   msh[512];  // (o*8+t)*16 normalized W_pos
    __shared__ __align__(16) float   ash[512];  // (o*8+t)*16 raw W_app

    const int tid    = threadIdx.x;
    const int o      = tid & 3;
    const int px     = (tid >> 2) & 15;
    const int ts     = tid >> 6;               // wave index = capsule slot
    const int wb     = blockIdx.x * TW;
    const int h      = blockIdx.y;
    const int n      = blockIdx.z >> 1;
    const int parity = blockIdx.z & 1;
    const int t      = parity + 2 * ts;        // capsule type for this wave
    const int w      = wb + px;
    const int pix    = h * IMG_W + w;

    // ---- precompute: packed conv weights ----
    for (int i = tid; i < 400; i += 256) {
        int o2  = i / 100;
        int rem = i - o2 * 100;
        int fp  = rem / 25;
        int k   = rem - fp * 25;
        wpk[i] = __floats2half2_rn(Wc[o2 * 200 + k * 8 + fp],
                                   Wc[o2 * 200 + k * 8 + 4 + fp]);
    }
    // ---- precompute: normalized pos matrices + raw app matrices ----
    if (tid < 128) {
        int c  = tid & 3;
        int tt = (tid >> 2) & 7;
        int oo = tid >> 5;
        const float* src = Wp + oo * 128 + tt * 16 + c;
        float v0 = src[0], v1 = src[4], v2 = src[8], v3 = src[12];
        float s = v0 * v0 + v1 * v1 + v2 * v2 + v3 * v3;
        float inv = 1.0f / sqrtf(fmaxf(s, 1e-12f));
        float* dst = msh + (oo * 8 + tt) * 16 + c;
        dst[0] = v0 * inv; dst[4] = v1 * inv; dst[8] = v2 * inv; dst[12] = v3 * inv;
    } else {
        int i = tid - 128;
        ((float4*)ash)[i] = ((const float4*)Wa)[i];
    }
    // ---- staging: interior 16 cols, 8 channels per ds_write_b128 ----
    {
        const int col = tid & 15;
        const int g   = tid >> 4;              // 0..15
        #pragma unroll
        for (int k = 0; k < 3; ++k) {
            int r = g + (k << 4);              // 0..47, valid < 40 = dy*8+cpg
            if (r < 40) {
                int dy  = r >> 3;
                int cpg = r & 7;
                int hh  = h + dy - 2;
                int c0  = cpg << 3;
                int chan = n * 128 + ((c0 >> 4) << 5) + (parity << 4) + (c0 & 15);
                float v[8];
                #pragma unroll
                for (int j = 0; j < 8; ++j) v[j] = 0.0f;
                if ((unsigned)hh < IMG_H) {
                    const float* src = x + (size_t)chan * HW + hh * IMG_W + wb + col;
                    #pragma unroll
                    for (int j = 0; j < 8; ++j) v[j] = src[(size_t)j * HW];
                }
                __half2 h4[4];
                #pragma unroll
                for (int j = 0; j < 4; ++j)
                    h4[j] = __floats2half2_rn(v[2 * j], v[2 * j + 1]);
                *(uint4*)&tile2[(dy * TC + 2 + col) * TS2 + (cpg << 2)] =
                    *(const uint4*)h4;
            }
        }
        // halo: x in {0,1,18,19}
        const int m  = tid & 3;
        const int xx = (m < 2) ? m : (m + TW);
        const int ww = wb - 2 + xx;
        const int rh = tid >> 2;               // 0..63
        #pragma unroll
        for (int k = 0; k < 3; ++k) {
            int r = rh + (k << 6);
            if (r < 160) {
                int dy = r >> 5;
                int cp = r & 31;
                int hh = h + dy - 2;
                int c0 = cp << 1;
                int chan = n * 128 + ((c0 >> 4) << 5) + (parity << 4) + (c0 & 15);
                float v0 = 0.0f, v1 = 0.0f;
                if ((unsigned)hh < IMG_H && (unsigned)ww < IMG_W) {
                    const float* src = x + (size_t)chan * HW + hh * IMG_W + ww;
                    v0 = src[0];
                    v1 = src[HW];
                }
                tile2[(dy * TC + xx) * TS2 + cp] = __floats2half2_rn(v0, v1);
            }
        }
    }
    __syncthreads();

    // ---- conv 5x5: one capsule per thread, packed fp16 ----
    __half2 rp2[8], ra2[8];
    const __half2 z2 = __float2half2_rn(0.0f);
    #pragma unroll
    for (int i = 0; i < 8; ++i) { rp2[i] = z2; ra2[i] = z2; }

    const __half2* wkb = &wpk[(o * 4 + (t >> 1)) * 25];
    #pragma unroll 1
    for (int dy = 0; dy < 5; ++dy) {
        #pragma unroll
        for (int dx = 0; dx < 5; ++dx) {
            const __half2* t2 = &tile2[(dy * TC + px + dx) * TS2 + (o << 3)];
            union { uint4 u; __half2 hh[4]; } A, B;
            A.u = *(const uint4*)t2;
            B.u = *(const uint4*)(t2 + 4);
            __half2 wv  = wkb[dy * 5 + dx];
            __half2 wp2 = __low2half2(wv);     // (pos,pos)
            __half2 wa2 = __high2half2(wv);    // (app,app)
            #pragma unroll
            for (int i = 0; i < 4; ++i) {
                rp2[i]     = __hfma2(A.hh[i], wp2, rp2[i]);
                ra2[i]     = __hfma2(A.hh[i], wa2, ra2[i]);
                rp2[4 + i] = __hfma2(B.hh[i], wp2, rp2[4 + i]);
                ra2[4 + i] = __hfma2(B.hh[i], wa2, ra2[4 + i]);
            }
        }
    }

    // ---- emit u_hat[32] (pos from LDS-normalized matrix + coord; app raw) ----
    float uh[32];
    {
        const float* mb = &msh[(o * 8 + t) * 16];
        float4 m0 = *(const float4*)(mb + 0);
        float4 m1 = *(const float4*)(mb + 4);
        float4 m2 = *(const float4*)(mb + 8);
        float4 m3 = *(const float4*)(mb + 12);
        m3.x += (float)w * (1.0f / 96.0f);     // coord add [row3,col0]
        m3.y += (float)h * (1.0f / 96.0f);     // [row3,col1]
        #pragma unroll
        for (int p0 = 0; p0 < 4; ++p0) {
            float r0 = __low2float(rp2[2 * p0]);
            float r1 = __high2float(rp2[2 * p0]);
            float r2 = __low2float(rp2[2 * p0 + 1]);
            float r3 = __high2float(rp2[2 * p0 + 1]);
            uh[p0 * 4 + 0] = r0 * m0.x + r1 * m1.x + r2 * m2.x + r3 * m3.x;
            uh[p0 * 4 + 1] = r0 * m0.y + r1 * m1.y + r2 * m2.y + r3 * m3.y;
            uh[p0 * 4 + 2] = r0 * m0.z + r1 * m1.z + r2 * m2.z + r3 * m3.z;
            uh[p0 * 4 + 3] = r0 * m0.w + r1 * m1.w + r2 * m2.w + r3 * m3.w;
        }
    }
    {
        const float* ab = &ash[(o * 8 + t) * 16];
        float4 a0 = *(const float4*)(ab + 0);
        float4 a1 = *(const float4*)(ab + 4);
        float4 a2 = *(const float4*)(ab + 8);
        float4 a3 = *(const float4*)(ab + 12);
        const float bias = Ba[o * 8 + t];
        #pragma unroll
        for (int p0 = 0; p0 < 4; ++p0) {
            float r0 = __low2float(ra2[2 * p0]) + bias;
            float r1 = __high2float(ra2[2 * p0]) + bias;
            float r2 = __low2float(ra2[2 * p0 + 1]) + bias;
            float r3 = __high2float(ra2[2 * p0 + 1]) + bias;
            uh[16 + p0 * 4 + 0] = r0 * a0.x + r1 * a1.x + r2 * a2.x + r3 * a3.x;
            uh[16 + p0 * 4 + 1] = r0 * a0.y + r1 * a1.y + r2 * a2.y + r3 * a3.y;
            uh[16 + p0 * 4 + 2] = r0 * a0.z + r1 * a1.z + r2 * a2.z + r3 * a3.z;
            uh[16 + p0 * 4 + 3] = r0 * a0.w + r1 * a1.w + r2 * a2.w + r3 * a3.w;
        }
    }

    route_store(uh, o, n * 8 + t, pix, out);
}

extern "C" void kernel_launch(void* const* d_in, const int* in_sizes, int n_in,
                              void* d_out, int out_size, void* d_ws, size_t ws_size,
                              hipStream_t stream) {
    const float* x  = (const float*)d_in[0];
    const float* Wc = (const float*)d_in[1];
    const float* Wp = (const float*)d_in[2];
    const float* Wa = (const float*)d_in[3];
    const float* Ba = (const float*)d_in[4];
    float* outp = (float*)d_out;

    caps_one_kernel<<<dim3(IMG_W / TW, IMG_H, 8), 256, 0, stream>>>(
        x, Wc, Wp, Wa, Ba, outp);
}